// Round 14
// baseline (176.759 us; speedup 1.0000x reference)
//
#include <hip/hip_runtime.h>
#include <math.h>

namespace {

constexpr int kBatch = 4;
constexpr int kN = 4096;
constexpr int kDim = 256;
constexpr int kHeads = 8;
constexpr int kK = 16;
constexpr float kEps = 1e-8f;

using u16 = unsigned short;
typedef __attribute__((ext_vector_type(8))) short short8;
typedef __attribute__((ext_vector_type(8))) u16 u16x8;
typedef __attribute__((ext_vector_type(4))) float f32x4;

__device__ __forceinline__ float b2f(u16 u) {
  union { unsigned int i; float f; } x; x.i = ((unsigned int)u) << 16; return x.f;
}
__device__ __forceinline__ u16 f2b(float f) {
  union { float f; unsigned int i; } x; x.f = f;
  unsigned int r = x.i + 0x7fffu + ((x.i >> 16) & 1u);  // RNE
  return (u16)(r >> 16);
}
__device__ __forceinline__ float gelu_exact(float x) {
  return 0.5f * x * (1.0f + erff(x * 0.70710678118654752f));
}
__device__ __forceinline__ void load_lds16(const u16* g, u16* l) {
  __builtin_amdgcn_global_load_lds(
      (const __attribute__((address_space(1))) unsigned int*)g,
      (__attribute__((address_space(3))) unsigned int*)l, 16, 0, 0);
}

// ---------------- LayerNorm body (one wave per row), bf16 out ----------------
template<bool ADD_TEMB>
__device__ __forceinline__ void ln_body(
    const float* __restrict__ x, const float* __restrict__ w,
    const float* __restrict__ bb, const float* __restrict__ temb,
    u16* __restrict__ out, int gt) {
  int row = gt >> 6;
  int lane = gt & 63;
  const float4* xr = (const float4*)(x + (size_t)row * kDim);
  float4 v = xr[lane];
  float s = v.x + v.y + v.z + v.w;
  #pragma unroll
  for (int off = 32; off; off >>= 1) s += __shfl_xor(s, off);
  float mean = s * (1.0f / kDim);
  float dx = v.x - mean, dy = v.y - mean, dz = v.z - mean, dw = v.w - mean;
  float ss = dx * dx + dy * dy + dz * dz + dw * dw;
  #pragma unroll
  for (int off = 32; off; off >>= 1) ss += __shfl_xor(ss, off);
  float rstd = rsqrtf(ss * (1.0f / kDim) + 1e-5f);
  float4 wv = ((const float4*)w)[lane];
  float4 bv = ((const float4*)bb)[lane];
  float ox = dx * rstd * wv.x + bv.x;
  float oy = dy * rstd * wv.y + bv.y;
  float oz = dz * rstd * wv.z + bv.z;
  float ow = dw * rstd * wv.w + bv.w;
  if (ADD_TEMB) {
    int bi = row >> 12;
    float4 t = ((const float4*)(temb + (size_t)bi * kDim))[lane];
    ox += t.x; oy += t.y; oz += t.z; ow += t.w;
  }
  ushort4 ob;
  ob.x = f2b(ox); ob.y = f2b(oy); ob.z = f2b(oz); ob.w = f2b(ow);
  ((ushort4*)(out + (size_t)row * kDim))[lane] = ob;
}

// ---------------- prep: wtrans (bx<192, 4 subgroups) + LN1 (192..1215) ----------------
__global__ __launch_bounds__(1024, 2) void prep_kernel(
    const float* __restrict__ x, const float* __restrict__ ln1w,
    const float* __restrict__ ln1b, const float* __restrict__ temb,
    u16* __restrict__ h_out,
    const float* __restrict__ Wq, const float* __restrict__ Wk,
    const float* __restrict__ Wv, const float* __restrict__ Wo,
    const float* __restrict__ W1, const float* __restrict__ W2,
    u16* __restrict__ Tq, u16* __restrict__ Tk,
    u16* __restrict__ Tv, u16* __restrict__ To,
    u16* __restrict__ T1, u16* __restrict__ T2) {
  __shared__ float tt4[4][1056];
  int tid = threadIdx.x;
  int bx = blockIdx.x;
  if (bx >= 192) {
    ln_body<true>(x, ln1w, ln1b, temb, h_out, (bx - 192) * 1024 + tid);
    return;
  }
  int sub = tid >> 8, stid = tid & 255;
  int task = bx * 4 + sub;                   // [0, 768)
  float* tt = tt4[sub];
  int seg = task >> 8, e = task & 255;
  const float* W; u16* T; int Kin, Nin, kt, nt;
  if (seg == 0) {
    int which = e >> 6, tl = e & 63;
    W = which == 0 ? Wq : which == 1 ? Wk : which == 2 ? Wv : Wo;
    T = which == 0 ? Tq : which == 1 ? Tk : which == 2 ? Tv : To;
    Kin = 256; Nin = 256; kt = tl >> 3; nt = tl & 7;
  } else if (seg == 1) {                     // W1[256][1024] -> T1[1024][256]
    W = W1; T = T1; Kin = 256; Nin = 1024; kt = e >> 5; nt = e & 31;
  } else {                                   // W2[1024][256] -> T2[256][1024]
    W = W2; T = T2; Kin = 1024; Nin = 256; kt = e >> 3; nt = e & 7;
  }
  int tx = stid & 31, ty = stid >> 5;        // 32 x 8
  #pragma unroll
  for (int rr = 0; rr < 4; ++rr) {
    int r = rr * 8 + ty;
    tt[r * 33 + tx] = W[(size_t)(kt * 32 + r) * Nin + nt * 32 + tx];
  }
  __syncthreads();
  #pragma unroll
  for (int rr = 0; rr < 4; ++rr) {
    int r = rr * 8 + ty;
    T[(size_t)(nt * 32 + r) * Kin + kt * 32 + tx] = f2b(tt[tx * 33 + r]);
  }
}

// ---------------- mid: topk (1024 blocks) ∥ qkv (768 blocks), 1024 threads ----------------
// bid < 1536: even -> topk (id = bid>>1), odd -> qkv (id = bid>>1);
// bid >= 1536: topk (id = bid - 768). Independent work, co-resident on CUs.
__global__ __launch_bounds__(1024, 2) void mid_kernel(
    const float* __restrict__ pos, const float* __restrict__ cptr,
    int* __restrict__ idx_out, float* __restrict__ dist_out,
    const u16* __restrict__ A,
    const u16* __restrict__ Bq, const u16* __restrict__ Bk, const u16* __restrict__ Bv,
    const float* __restrict__ bq, const float* __restrict__ bk, const float* __restrict__ bv,
    u16* __restrict__ qo, u16* __restrict__ ko, u16* __restrict__ vo) {
  __shared__ float4 ps[kN];  // 64 KB; qkv path aliases 32 KB of it
  int tid = threadIdx.x;
  int bid = blockIdx.x;
  bool is_qkv = (bid < 1536) && (bid & 1);

  if (is_qkv) {
    // ---- qkv: 128x128 tile, 16 waves of 32x32, BK=64, K=256 ----
    u16* Al = (u16*)ps;              // [128][64]
    u16* Bl = (u16*)ps + 128 * 64;   // [128][64]
    int qid = bid >> 1;              // 0..767
    int bx = qid / 6, y = qid % 6;
    int sel = y >> 1, by = y & 1;
    const u16* Bt = sel == 0 ? Bq : sel == 1 ? Bk : Bv;
    const float* bias = sel == 0 ? bq : sel == 1 ? bk : bv;
    u16* C = sel == 0 ? qo : sel == 1 ? ko : vo;
    int wv = tid >> 6, ln = tid & 63;
    int wr = wv >> 2, wc = wv & 3;
    int lhi = ln >> 4, llo = ln & 15;
    int bm = bx * 128, bn = by * 128;

    f32x4 zero = {0.f, 0.f, 0.f, 0.f};
    f32x4 acc[2][2];
    #pragma unroll
    for (int mi = 0; mi < 2; ++mi)
      #pragma unroll
      for (int ni = 0; ni < 2; ++ni) acc[mi][ni] = zero;

    for (int k0 = 0; k0 < 256; k0 += 64) {
      if (k0) __syncthreads();
      {  // A: 128 rows x 8 octets = 1024 loads, 1/thread
        int r = tid >> 3, o = tid & 7;
        load_lds16(A + (size_t)(bm + r) * 256 + k0 + ((o ^ (r & 7)) << 3),
                   &Al[(wv * 64) * 8]);
        load_lds16(Bt + (size_t)(bn + r) * 256 + k0 + ((o ^ (r & 7)) << 3),
                   &Bl[(wv * 64) * 8]);
      }
      __syncthreads();
      #pragma unroll
      for (int ks = 0; ks < 64; ks += 32) {
        short8 af[2], bf[2];
        #pragma unroll
        for (int mi = 0; mi < 2; ++mi) {
          int row = wr * 32 + mi * 16 + llo;
          int oct = ((ks >> 3) + lhi) ^ (llo & 7);
          af[mi] = *(const short8*)&Al[row * 64 + oct * 8];
        }
        #pragma unroll
        for (int ni = 0; ni < 2; ++ni) {
          int brow = wc * 32 + ni * 16 + llo;
          int oct = ((ks >> 3) + lhi) ^ (llo & 7);
          bf[ni] = *(const short8*)&Bl[brow * 64 + oct * 8];
        }
        #pragma unroll
        for (int mi = 0; mi < 2; ++mi)
          #pragma unroll
          for (int ni = 0; ni < 2; ++ni)
            acc[mi][ni] = __builtin_amdgcn_mfma_f32_16x16x32_bf16(
                af[mi], bf[ni], acc[mi][ni], 0, 0, 0);
      }
    }
    #pragma unroll
    for (int mi = 0; mi < 2; ++mi) {
      #pragma unroll
      for (int r = 0; r < 4; ++r) {
        int row = bm + wr * 32 + mi * 16 + lhi * 4 + r;
        #pragma unroll
        for (int ni = 0; ni < 2; ++ni) {
          int col = bn + wc * 32 + ni * 16 + llo;
          C[(size_t)row * 256 + col] = f2b(acc[mi][ni][r] + bias[col]);
        }
      }
    }
    return;
  }

  // ---- topk path (R12-proven: numden filter + packed-key insert) ----
  int tkid = (bid < 1536) ? (bid >> 1) : (bid - 768);
  int wave = tid >> 6, ln = tid & 63;
  int row = tkid * 16 + wave;          // blocks never straddle batches
  int b = row >> 12;
  float c = cptr[0];
  const float* pb = pos + (size_t)b * kN * 3;
  for (int j = tid; j < kN; j += 1024) {   // strided: conflict-free LDS writes
    float px = pb[j * 3 + 0], py = pb[j * 3 + 1], pz = pb[j * 3 + 2];
    ps[j] = make_float4(px, py, pz, c * (px * px + py * py + pz * pz));
  }
  __syncthreads();

  int i = row & (kN - 1);
  float4 pi = ps[i];
  float wi = pi.w, oi = 1.0f - wi;
  float sx = 2.0f * c * pi.x, sy = 2.0f * c * pi.y, sz = 2.0f * c * pi.z;

  auto numden = [&](int j, float& num, float& den) {
    float4 pj = ps[j];
    float tt = wi + pj.w;
    tt = fmaf(-sx, pj.x, tt);
    tt = fmaf(-sy, pj.y, tt);
    tt = fmaf(-sz, pj.z, tt);
    num = fmaxf(tt, 0.0f);
    den = fmaf(-oi, pj.w, oi);
  };
  auto packkey = [&](float num, float den, int j) -> unsigned {
    float r = num * __builtin_amdgcn_rcpf(den);
    union { float f; unsigned u; } cv; cv.f = r;
    return (cv.u & 0xFFFFF000u) | (unsigned)j;
  };
  auto inflate = [&](unsigned T) -> float {
    union { unsigned u; float f; } tv; tv.u = T & 0xFFFFF000u;
    return fmaf(tv.f, 0.001f, tv.f);
  };

  float n0, d0;
  numden(ln, n0, d0);
  unsigned lpk = packkey(n0, d0, ln);
  #pragma unroll
  for (int kk = 2; kk <= 64; kk <<= 1) {
    #pragma unroll
    for (int jj = kk >> 1; jj >= 1; jj >>= 1) {
      unsigned ov = (unsigned)__shfl_xor((int)lpk, jj);
      bool keepMin = (((ln & kk) == 0) == ((ln & jj) == 0));
      bool less = ov < lpk;
      if (keepMin ? less : !less) lpk = ov;
    }
  }
  float Tf = inflate((unsigned)__builtin_amdgcn_readlane((int)lpk, 15));

  auto processGroup = [&](float num, float den, int base) {
    unsigned long long m = __ballot(num < Tf * den);
    if (m) {
      unsigned cpk = packkey(num, den, base + ln);  // wave-wide, once per group
      do {
        int src = __ffsll(m) - 1;
        m &= m - 1;
        unsigned npk = (unsigned)__builtin_amdgcn_readlane((int)cpk, src);
        unsigned pv = (unsigned)__builtin_amdgcn_update_dpp(
            0, (int)lpk, 0x111 /*row_shr:1*/, 0xF, 0xF, false);
        bool gt = lpk > npk;
        bool take = gt && ((ln == 0) || (pv <= npk));
        lpk = take ? npk : (gt ? pv : lpk);
      } while (m);
      Tf = inflate((unsigned)__builtin_amdgcn_readlane((int)lpk, 15));
    }
  };

  int t = 1;
  for (; t + 3 < 64; t += 4) {
    float a0, b0, a1, b1, a2, b2, a3, b3;
    numden(ln + (t + 0) * 64, a0, b0);
    numden(ln + (t + 1) * 64, a1, b1);
    numden(ln + (t + 2) * 64, a2, b2);
    numden(ln + (t + 3) * 64, a3, b3);
    processGroup(a0, b0, (t + 0) * 64);
    processGroup(a1, b1, (t + 1) * 64);
    processGroup(a2, b2, (t + 2) * 64);
    processGroup(a3, b3, (t + 3) * 64);
  }
  for (; t < 64; ++t) {
    float a0, b0;
    numden(ln + t * 64, a0, b0);
    processGroup(a0, b0, t * 64);
  }

  if (ln < kK) {
    int j = (int)(lpk & 0xFFFu);
    // exact recompute (full-precision divide + eps), matching the reference formula
    float4 pj = ps[j];
    float tt = wi + pj.w;
    tt = fmaf(-sx, pj.x, tt);
    tt = fmaf(-sy, pj.y, tt);
    tt = fmaf(-sz, pj.z, tt);
    float num = 2.0f * fmaxf(tt, 0.0f);
    float den = fmaf(-oi, pj.w, oi) + kEps;
    float arg = fmaxf(1.0f + num / den, 1.0f);
    float rs = 1.0f / sqrtf(c);
    idx_out[(size_t)row * kK + ln] = j;
    dist_out[(size_t)row * kK + ln] = acoshf(arg) * rs;
  }
}

// ---------------- bf16 MFMA GEMM: C[M,N] = A[M,K] @ Bt[N,K]^T ----------------
template<int EPI, int BN>
__device__ __forceinline__ void gemm_body(
    const u16* __restrict__ A, const u16* __restrict__ Bt,
    const float* __restrict__ bias, const float* __restrict__ R,
    float* __restrict__ Cf, u16* __restrict__ Cbf,
    int N, int K, int bx, int by) {
  constexpr int NI = BN / 32;          // B fragments per wave
  constexpr int BK = 64;               // K-chunk
  __shared__ u16 Al[128 * BK];
  __shared__ u16 Bl[BN * BK];
  int tid = threadIdx.x;
  int wv = tid >> 6, ln = tid & 63;
  int wr = wv >> 1, wc = wv & 1;
  int lhi = ln >> 4, llo = ln & 15;
  int bm = bx * 128, bn = by * BN;

  f32x4 zero = {0.f, 0.f, 0.f, 0.f};
  f32x4 acc[4][NI];
  #pragma unroll
  for (int mi = 0; mi < 4; ++mi)
    #pragma unroll
    for (int ni = 0; ni < NI; ++ni) acc[mi][ni] = zero;

  for (int k0 = 0; k0 < K; k0 += BK) {
    if (k0) __syncthreads();
    #pragma unroll
    for (int i = 0; i < 128 * BK / (8 * 256); ++i) {   // 4
      int f = i * 256 + tid;
      int r = f >> 3, o = f & 7;
      load_lds16(A + (size_t)(bm + r) * K + k0 + ((o ^ (r & 7)) << 3),
                 &Al[(i * 256 + wv * 64) * 8]);
    }
    #pragma unroll
    for (int i = 0; i < BN * BK / (8 * 256); ++i) {    // 4 or 2
      int f = i * 256 + tid;
      int r = f >> 3, o = f & 7;
      load_lds16(Bt + (size_t)(bn + r) * K + k0 + ((o ^ (r & 7)) << 3),
                 &Bl[(i * 256 + wv * 64) * 8]);
    }
    __syncthreads();
    #pragma unroll
    for (int ks = 0; ks < BK; ks += 32) {
      short8 af[4], bf[NI];
      #pragma unroll
      for (int mi = 0; mi < 4; ++mi) {
        int row = wr * 64 + mi * 16 + llo;
        int oct = ((ks >> 3) + lhi) ^ (llo & 7);
        af[mi] = *(const short8*)&Al[row * BK + oct * 8];
      }
      #pragma unroll
      for (int ni = 0; ni < NI; ++ni) {
        int row = wc * (BN / 2) + ni * 16 + llo;
        int oct = ((ks >> 3) + lhi) ^ (llo & 7);
        bf[ni] = *(const short8*)&Bl[row * BK + oct * 8];
      }
      #pragma unroll
      for (int mi = 0; mi < 4; ++mi)
        #pragma unroll
        for (int ni = 0; ni < NI; ++ni)
          acc[mi][ni] = __builtin_amdgcn_mfma_f32_16x16x32_bf16(
              af[mi], bf[ni], acc[mi][ni], 0, 0, 0);
    }
  }

  #pragma unroll
  for (int mi = 0; mi < 4; ++mi) {
    #pragma unroll
    for (int r = 0; r < 4; ++r) {
      int row = bm + wr * 64 + mi * 16 + lhi * 4 + r;
      #pragma unroll
      for (int ni = 0; ni < NI; ++ni) {
        int col = bn + wc * (BN / 2) + ni * 16 + llo;
        float val = acc[mi][ni][r] + bias[col];
        if (EPI == 1) {
          val += R[(size_t)row * N + col];
          Cf[(size_t)row * N + col] = val;
        } else {
          if (EPI == 2) val = gelu_exact(val);
          Cbf[(size_t)row * N + col] = f2b(val);
        }
      }
    }
  }
}

// 1-D grid + XCD-chunk swizzle (by fast -> A re-reads hit local L2)
template<int EPI, int BN, int NY>
__global__ __launch_bounds__(256) void gemm_swz_kernel(
    const u16* __restrict__ A, const u16* __restrict__ Bt,
    const float* __restrict__ bias, const float* __restrict__ R,
    float* __restrict__ Cf, u16* __restrict__ Cbf, int N, int K) {
  int cpx = gridDim.x >> 3;            // grid multiple of 8
  int orig = blockIdx.x;
  int swz = (orig & 7) * cpx + (orig >> 3);
  int bx = swz / NY, by = swz % NY;
  gemm_body<EPI, BN>(A, Bt, bias, R, Cf, Cbf, N, K, bx, by);
}

// ---------------- fused attn + Wo GEMM + residual + LN2 ----------------
__global__ __launch_bounds__(512) void awo_ln_kernel(
    const u16* __restrict__ q, const u16* __restrict__ k,
    const u16* __restrict__ v, const int* __restrict__ nidx,
    const float* __restrict__ ndist, const float* __restrict__ log_tau,
    const u16* __restrict__ Bt, const float* __restrict__ bo,
    const float* __restrict__ xres,
    const float* __restrict__ ln2w, const float* __restrict__ ln2b,
    float* __restrict__ x2, u16* __restrict__ tln) {
  __shared__ u16 Al[64 * 256];     // 32 KB, octet-swizzled, full K
  __shared__ u16 Bl[256 * 64];     // 32 KB
  __shared__ float red[4][64][2];  // 2 KB
  int tid = threadIdx.x;
  int bm = blockIdx.x * 64;

  // ---- phase 1: gathered attention ----
  {
    int rl = tid >> 3, h = tid & 7;
    int row = bm + rl;
    int b = row >> 12;
    float rtau = 1.0f / (expf(log_tau[0]) + kEps);
    const u16x8* qr = (const u16x8*)(q + (size_t)row * kDim + h * 32);
    float qf[32];
    #pragma unroll
    for (int cch = 0; cch < 4; ++cch) {
      u16x8 u = qr[cch];
      #pragma unroll
      for (int e = 0; e < 8; ++e) qf[cch * 8 + e] = b2f(u[e]);
    }
    int njs[kK];
    float sc[kK];
    const int* ir = nidx + (size_t)row * kK;
    const float* dr = ndist + (size_t)row * kK;
    float smax = -1e30f;
    #pragma unroll
    for (int j = 0; j < kK; ++j) {
      int nj = ir[j];
      njs[j] = nj;
      const u16x8* kr = (const u16x8*)(k + ((size_t)b * kN + nj) * kDim + h * 32);
      float dot = 0.0f;
      #pragma unroll
      for (int cch = 0; cch < 4; ++cch) {
        u16x8 u = kr[cch];
        #pragma unroll
        for (int e = 0; e < 8; ++e) dot = fmaf(qf[cch * 8 + e], b2f(u[e]), dot);
      }
      float s = dot * 0.17677669529663687f - dr[j] * rtau;  // 1/sqrt(32)
      sc[j] = s;
      smax = fmaxf(smax, s);
    }
    float sum = 0.0f;
    #pragma unroll
    for (int j = 0; j < kK; ++j) { sc[j] = expf(sc[j] - smax); sum += sc[j]; }
    float rsum = 1.0f / sum;
    float o[32];
    #pragma unroll
    for (int d = 0; d < 32; ++d) o[d] = 0.0f;
    #pragma unroll
    for (int j = 0; j < kK; ++j) {
      float p = sc[j] * rsum;
      const u16x8* vr = (const u16x8*)(v + ((size_t)b * kN + njs[j]) * kDim + h * 32);
      #pragma unroll
      for (int cch = 0; cch < 4; ++cch) {
        u16x8 u = vr[cch];
        #pragma unroll
        for (int e = 0; e < 8; ++e) o[cch * 8 + e] = fmaf(p, b2f(u[e]), o[cch * 8 + e]);
      }
    }
    #pragma unroll
    for (int cch = 0; cch < 4; ++cch) {
      u16x8 po;
      #pragma unroll
      for (int e = 0; e < 8; ++e) po[e] = f2b(o[cch * 8 + e]);
      int oct = h * 4 + cch;
      *(u16x8*)&Al[rl * 256 + ((oct ^ (rl & 7)) << 3)] = po;
    }
  }
  __syncthreads();

  // ---- phase 2: GEMM (A resident in LDS) ----
  int wv = tid >> 6, ln = tid & 63;
  int wr = wv >> 2, wc = wv & 3;
  int lhi = ln >> 4, llo = ln & 15;

  f32x4 zero = {0.f, 0.f, 0.f, 0.f};
  f32x4 acc[2][4];
  #pragma unroll
  for (int mi = 0; mi < 2; ++mi)
    #pragma unroll
    for (int ni = 0; ni < 4; ++ni) acc[mi][ni] = zero;

  for (int k0 = 0; k0 < 256; k0 += 64) {
    if (k0) __syncthreads();
    #pragma unroll
    for (int i = 0; i < 4; ++i) {  // B: 256x64
      int f = i * 512 + tid, r = f >> 3, o = f & 7;
      load_lds16(Bt + (size_t)r * 256 + k0 + ((o ^ (r & 7)) << 3),
                 &Bl[((i * 8 + wv) * 64) * 8]);
    }
    __syncthreads();
    #pragma unroll
    for (int ks = 0; ks < 64; ks += 32) {
      short8 af[2], bf[4];
      #pragma unroll
      for (int mi = 0; mi < 2; ++mi) {
        int row = wr * 32 + mi * 16 + llo;
        int octg = ((k0 + ks) >> 3) + lhi;
        af[mi] = *(const short8*)&Al[row * 256 + ((octg ^ (llo & 7)) << 3)];
      }
      #pragma unroll
      for (int ni = 0; ni < 4; ++ni) {
        int brow = wc * 64 + ni * 16 + llo;
        int oct = ((ks >> 3) + lhi) ^ (llo & 7);
        bf[ni] = *(const short8*)&Bl[brow * 64 + oct * 8];
      }
      #pragma unroll
      for (int mi = 0; mi < 2; ++mi)
        #pragma unroll
        for (int ni = 0; ni < 4; ++ni)
          acc[mi][ni] = __builtin_amdgcn_mfma_f32_16x16x32_bf16(
              af[mi], bf[ni], acc[mi][ni], 0, 0, 0);
    }
  }

  float psum[2][4], psq[2][4];
  #pragma unroll
  for (int mi = 0; mi < 2; ++mi) {
    #pragma unroll
    for (int r = 0; r < 4; ++r) {
      int row = bm + wr * 32 + mi * 16 + lhi * 4 + r;
      float s = 0.0f, qv = 0.0f;
      #pragma unroll
      for (int ni = 0; ni < 4; ++ni) {
        int col = wc * 64 + ni * 16 + llo;
        float vv = acc[mi][ni][r] + bo[col] + xres[(size_t)row * 256 + col];
        acc[mi][ni][r] = vv;
        s += vv;
        qv = fmaf(vv, vv, qv);
      }
      #pragma unroll
      for (int off = 1; off < 16; off <<= 1) {
        s += __shfl_xor(s, off);
        qv += __shfl_xor(qv, off);
      }
      psum[mi][r] = s; psq[mi][r] = qv;
    }
  }
  if (llo == 0) {
    #pragma unroll
    for (int mi = 0; mi < 2; ++mi)
      #pragma unroll
      for (int r = 0; r < 4; ++r) {
        int rl = wr * 32 + mi * 16 + lhi * 4 + r;
        red[wc][rl][0] = psum[mi][r];
        red[wc][rl][1] = psq[mi][r];
      }
  }
  __syncthreads();
  constexpr float rn = 1.0f / 256.0f;
  #pragma unroll
  for (int mi = 0; mi < 2; ++mi) {
    #pragma unroll
    for (int r = 0; r < 4; ++r) {
      int rl = wr * 32 + mi * 16 + lhi * 4 + r;
      int row = bm + rl;
      float S = red[0][rl][0] + red[1][rl][0] + red[2][rl][0] + red[3][rl][0];
      float Q = red[0][rl][1] + red[1][rl][1] + red[2][rl][1] + red[3][rl][1];
      float mean = S * rn;
      float var = Q * rn - mean * mean;
      float rstd = rsqrtf(var + 1e-5f);
      #pragma unroll
      for (int ni = 0; ni < 4; ++ni) {
        int col = wc * 64 + ni * 16 + llo;
        float vv = acc[mi][ni][r];
        x2[(size_t)row * 256 + col] = vv;
        tln[(size_t)row * 256 + col] =
            f2b((vv - mean) * rstd * ln2w[col] + ln2b[col]);
      }
    }
  }
}

}  // namespace

extern "C" void kernel_launch(void* const* d_in, const int* in_sizes, int n_in,
                              void* d_out, int out_size, void* d_ws, size_t ws_size,
                              hipStream_t stream) {
  const float* x    = (const float*)d_in[0];
  const float* pos  = (const float*)d_in[1];
  const float* c    = (const float*)d_in[2];
  const float* temb = (const float*)d_in[3];
  const float* Wq   = (const float*)d_in[4];
  const float* bq   = (const float*)d_in[5];
  const float* Wk   = (const float*)d_in[6];
  const float* bk   = (const float*)d_in[7];
  const float* Wv   = (const float*)d_in[8];
  const float* bv   = (const float*)d_in[9];
  const float* Wo   = (const float*)d_in[10];
  const float* bo   = (const float*)d_in[11];
  const float* W1   = (const float*)d_in[12];
  const float* b1   = (const float*)d_in[13];
  const float* W2   = (const float*)d_in[14];
  const float* b2   = (const float*)d_in[15];
  const float* ln1w = (const float*)d_in[16];
  const float* ln1b = (const float*)d_in[17];
  const float* ln2w = (const float*)d_in[18];
  const float* ln2b = (const float*)d_in[19];
  const float* ltau = (const float*)d_in[20];

  const size_t MB = 1ull << 20;
  char* w = (char*)d_ws;
  u16*   h_bf  = (u16*)(w + 0 * MB);               // [M,256] bf16 (8 MB); reused as tln
  u16*   qb    = (u16*)(w + 8 * MB);
  u16*   kb    = (u16*)(w + 16 * MB);
  u16*   vb    = (u16*)(w + 24 * MB);
  float* x2    = (float*)(w + 40 * MB);            // [M,256] f32 (16 MB)
  u16*   g_bf  = (u16*)(w + 56 * MB);              // [M,1024] bf16 (32 MB)
  u16*   wq_t  = (u16*)(w + 88 * MB);              // 128 KB each
  u16*   wk_t  = wq_t + 65536;
  u16*   wv_t  = wq_t + 2 * 65536;
  u16*   wo_t  = wq_t + 3 * 65536;
  u16*   w1_t  = (u16*)(w + 89 * MB);              // [1024][256] (512 KB)
  u16*   w2_t  = (u16*)(w + 89 * MB + 512 * 1024); // [256][1024] (512 KB)
  int*   kidx  = (int*)(w + 90 * MB);              // [M,16]
  float* kdst  = (float*)(w + 91 * MB);            // [M,16]
  u16*   tln   = h_bf;

  // 1. prep: wtrans (192 blk) + LN1 (1024 blk)
  hipLaunchKernelGGL(prep_kernel, dim3(1216), dim3(1024), 0, stream,
                     x, ln1w, ln1b, temb, h_bf,
                     Wq, Wk, Wv, Wo, W1, W2, wq_t, wk_t, wv_t, wo_t, w1_t, w2_t);
  // 2. mid: topk (1024 blk) ∥ qkv (768 blk) — independent, co-resident
  hipLaunchKernelGGL(mid_kernel, dim3(1792), dim3(1024), 0, stream,
                     pos, c, kidx, kdst,
                     h_bf, wq_t, wk_t, wv_t, bq, bk, bv, qb, kb, vb);
  // 3. gathered attention + Wo + residual + LN2 (fused)
  hipLaunchKernelGGL(awo_ln_kernel, dim3(256), dim3(512), 0, stream,
                     qb, kb, vb, kidx, kdst, ltau,
                     wo_t, bo, x, ln2w, ln2b, x2, tln);
  // 4. g = gelu(tln @ W1 + b1)  (bf16), swizzled
  hipLaunchKernelGGL((gemm_swz_kernel<2, 128, 8>), dim3(1024), dim3(256), 0, stream,
                     tln, w1_t, b1, nullptr, (float*)nullptr, g_bf, 1024, 256);
  // 5. out = x2 + g @ W2 + b2  (f32), swizzled
  hipLaunchKernelGGL((gemm_swz_kernel<1, 64, 4>), dim3(512), dim3(256), 0, stream,
                     g_bf, w2_t, b2, x2, (float*)d_out, (u16*)nullptr, 256, 1024);
}

// Round 15
// 161.554 us; speedup vs baseline: 1.0941x; 1.0941x over previous
//
#include <hip/hip_runtime.h>
#include <math.h>

namespace {

constexpr int kBatch = 4;
constexpr int kN = 4096;
constexpr int kDim = 256;
constexpr int kHeads = 8;
constexpr int kK = 16;
constexpr float kEps = 1e-8f;

using u16 = unsigned short;
typedef __attribute__((ext_vector_type(8))) short short8;
typedef __attribute__((ext_vector_type(8))) u16 u16x8;
typedef __attribute__((ext_vector_type(4))) float f32x4;

__device__ __forceinline__ float b2f(u16 u) {
  union { unsigned int i; float f; } x; x.i = ((unsigned int)u) << 16; return x.f;
}
__device__ __forceinline__ u16 f2b(float f) {
  union { float f; unsigned int i; } x; x.f = f;
  unsigned int r = x.i + 0x7fffu + ((x.i >> 16) & 1u);  // RNE
  return (u16)(r >> 16);
}
__device__ __forceinline__ float gelu_exact(float x) {
  return 0.5f * x * (1.0f + erff(x * 0.70710678118654752f));
}
__device__ __forceinline__ void load_lds16(const u16* g, u16* l) {
  __builtin_amdgcn_global_load_lds(
      (const __attribute__((address_space(1))) unsigned int*)g,
      (__attribute__((address_space(3))) unsigned int*)l, 16, 0, 0);
}

// ---------------- LayerNorm body (one wave per row), bf16 out ----------------
template<bool ADD_TEMB>
__device__ __forceinline__ void ln_body(
    const float* __restrict__ x, const float* __restrict__ w,
    const float* __restrict__ bb, const float* __restrict__ temb,
    u16* __restrict__ out, int gt) {
  int row = gt >> 6;
  int lane = gt & 63;
  const float4* xr = (const float4*)(x + (size_t)row * kDim);
  float4 v = xr[lane];
  float s = v.x + v.y + v.z + v.w;
  #pragma unroll
  for (int off = 32; off; off >>= 1) s += __shfl_xor(s, off);
  float mean = s * (1.0f / kDim);
  float dx = v.x - mean, dy = v.y - mean, dz = v.z - mean, dw = v.w - mean;
  float ss = dx * dx + dy * dy + dz * dz + dw * dw;
  #pragma unroll
  for (int off = 32; off; off >>= 1) ss += __shfl_xor(ss, off);
  float rstd = rsqrtf(ss * (1.0f / kDim) + 1e-5f);
  float4 wv = ((const float4*)w)[lane];
  float4 bv = ((const float4*)bb)[lane];
  float ox = dx * rstd * wv.x + bv.x;
  float oy = dy * rstd * wv.y + bv.y;
  float oz = dz * rstd * wv.z + bv.z;
  float ow = dw * rstd * wv.w + bv.w;
  if (ADD_TEMB) {
    int bi = row >> 12;
    float4 t = ((const float4*)(temb + (size_t)bi * kDim))[lane];
    ox += t.x; oy += t.y; oz += t.z; ow += t.w;
  }
  ushort4 ob;
  ob.x = f2b(ox); ob.y = f2b(oy); ob.z = f2b(oz); ob.w = f2b(ow);
  ((ushort4*)(out + (size_t)row * kDim))[lane] = ob;
}

// ---------------- fused front: topk (bx<1024) + wtrans (1024..1215) + LN1 (rest) ----------------
__global__ __launch_bounds__(1024, 2) void front_kernel(
    const float* __restrict__ pos, const float* __restrict__ cptr,
    int* __restrict__ idx_out, float* __restrict__ dist_out,
    const float* __restrict__ x, const float* __restrict__ ln1w,
    const float* __restrict__ ln1b, const float* __restrict__ temb,
    u16* __restrict__ h_out,
    const float* __restrict__ Wq, const float* __restrict__ Wk,
    const float* __restrict__ Wv, const float* __restrict__ Wo,
    const float* __restrict__ W1, const float* __restrict__ W2,
    u16* __restrict__ Tq, u16* __restrict__ Tk,
    u16* __restrict__ Tv, u16* __restrict__ To,
    u16* __restrict__ T1, u16* __restrict__ T2) {
  __shared__ float4 ps[kN];  // 64 KB (union)
  int tid = threadIdx.x;
  int bx = blockIdx.x;

  if (bx >= 1024) {
    if (bx < 1216) {
      // ---- weight transpose-convert: 4 subgroups of 256 threads ----
      int sub = tid >> 8, stid = tid & 255;
      int task = (bx - 1024) * 4 + sub;          // [0, 768)
      float* tt = (float*)ps + sub * 1056;       // 32x33 tile slice
      int seg = task >> 8, e = task & 255;
      const float* W; u16* T; int Kin, Nin, kt, nt;
      if (seg == 0) {
        int which = e >> 6, tl = e & 63;
        W = which == 0 ? Wq : which == 1 ? Wk : which == 2 ? Wv : Wo;
        T = which == 0 ? Tq : which == 1 ? Tk : which == 2 ? Tv : To;
        Kin = 256; Nin = 256; kt = tl >> 3; nt = tl & 7;
      } else if (seg == 1) {                     // W1[256][1024] -> T1[1024][256]
        W = W1; T = T1; Kin = 256; Nin = 1024; kt = e >> 5; nt = e & 31;
      } else {                                   // W2[1024][256] -> T2[256][1024]
        W = W2; T = T2; Kin = 1024; Nin = 256; kt = e >> 3; nt = e & 7;
      }
      int tx = stid & 31, ty = stid >> 5;        // 32 x 8
      #pragma unroll
      for (int rr = 0; rr < 4; ++rr) {
        int r = rr * 8 + ty;
        tt[r * 33 + tx] = W[(size_t)(kt * 32 + r) * Nin + nt * 32 + tx];
      }
      __syncthreads();
      #pragma unroll
      for (int rr = 0; rr < 4; ++rr) {
        int r = rr * 8 + ty;
        T[(size_t)(nt * 32 + r) * Kin + kt * 32 + tx] = f2b(tt[tx * 33 + r]);
      }
    } else {
      // ---- LN1 path: 1024 blocks, 16 rows each ----
      ln_body<true>(x, ln1w, ln1b, temb, h_out, (bx - 1216) * 1024 + tid);
    }
    return;
  }

  // ---- topk path (R12-proven: numden filter + packed-key insert) ----
  int wave = tid >> 6, ln = tid & 63;
  int row = bx * 16 + wave;            // blocks never straddle batches
  int b = row >> 12;
  float c = cptr[0];
  const float* pb = pos + (size_t)b * kN * 3;
  for (int j = tid; j < kN; j += 1024) {   // strided: conflict-free LDS writes
    float px = pb[j * 3 + 0], py = pb[j * 3 + 1], pz = pb[j * 3 + 2];
    ps[j] = make_float4(px, py, pz, c * (px * px + py * py + pz * pz));
  }
  __syncthreads();

  int i = row & (kN - 1);
  float4 pi = ps[i];
  float wi = pi.w, oi = 1.0f - wi;
  float sx = 2.0f * c * pi.x, sy = 2.0f * c * pi.y, sz = 2.0f * c * pi.z;

  auto numden = [&](int j, float& num, float& den) {
    float4 pj = ps[j];
    float tt = wi + pj.w;
    tt = fmaf(-sx, pj.x, tt);
    tt = fmaf(-sy, pj.y, tt);
    tt = fmaf(-sz, pj.z, tt);
    num = fmaxf(tt, 0.0f);
    den = fmaf(-oi, pj.w, oi);
  };
  auto packkey = [&](float num, float den, int j) -> unsigned {
    float r = num * __builtin_amdgcn_rcpf(den);
    union { float f; unsigned u; } cv; cv.f = r;
    return (cv.u & 0xFFFFF000u) | (unsigned)j;
  };
  auto inflate = [&](unsigned T) -> float {
    union { unsigned u; float f; } tv; tv.u = T & 0xFFFFF000u;
    return fmaf(tv.f, 0.001f, tv.f);
  };

  // bootstrap: bitonic sort of candidates 0..63 (ascending packed key)
  float n0, d0;
  numden(ln, n0, d0);
  unsigned lpk = packkey(n0, d0, ln);
  #pragma unroll
  for (int kk = 2; kk <= 64; kk <<= 1) {
    #pragma unroll
    for (int jj = kk >> 1; jj >= 1; jj >>= 1) {
      unsigned ov = (unsigned)__shfl_xor((int)lpk, jj);
      bool keepMin = (((ln & kk) == 0) == ((ln & jj) == 0));
      bool less = ov < lpk;
      if (keepMin ? less : !less) lpk = ov;
    }
  }
  float Tf = inflate((unsigned)__builtin_amdgcn_readlane((int)lpk, 15));

  auto processGroup = [&](float num, float den, int base) {
    unsigned long long m = __ballot(num < Tf * den);
    if (m) {
      unsigned cpk = packkey(num, den, base + ln);  // wave-wide, once per group
      do {
        int src = __ffsll(m) - 1;
        m &= m - 1;
        unsigned npk = (unsigned)__builtin_amdgcn_readlane((int)cpk, src);
        unsigned pv = (unsigned)__builtin_amdgcn_update_dpp(
            0, (int)lpk, 0x111 /*row_shr:1*/, 0xF, 0xF, false);
        bool gt = lpk > npk;
        bool take = gt && ((ln == 0) || (pv <= npk));
        lpk = take ? npk : (gt ? pv : lpk);
      } while (m);
      Tf = inflate((unsigned)__builtin_amdgcn_readlane((int)lpk, 15));
    }
  };

  int t = 1;
  for (; t + 3 < 64; t += 4) {
    float a0, b0, a1, b1, a2, b2, a3, b3;
    numden(ln + (t + 0) * 64, a0, b0);
    numden(ln + (t + 1) * 64, a1, b1);
    numden(ln + (t + 2) * 64, a2, b2);
    numden(ln + (t + 3) * 64, a3, b3);
    processGroup(a0, b0, (t + 0) * 64);
    processGroup(a1, b1, (t + 1) * 64);
    processGroup(a2, b2, (t + 2) * 64);
    processGroup(a3, b3, (t + 3) * 64);
  }
  for (; t < 64; ++t) {
    float a0, b0;
    numden(ln + t * 64, a0, b0);
    processGroup(a0, b0, t * 64);
  }

  if (ln < kK) {
    int j = (int)(lpk & 0xFFFu);
    // exact recompute (full-precision divide + eps), matching the reference formula
    float4 pj = ps[j];
    float tt = wi + pj.w;
    tt = fmaf(-sx, pj.x, tt);
    tt = fmaf(-sy, pj.y, tt);
    tt = fmaf(-sz, pj.z, tt);
    float num = 2.0f * fmaxf(tt, 0.0f);
    float den = fmaf(-oi, pj.w, oi) + kEps;
    float arg = fmaxf(1.0f + num / den, 1.0f);
    float rs = 1.0f / sqrtf(c);
    idx_out[(size_t)row * kK + ln] = j;
    dist_out[(size_t)row * kK + ln] = acoshf(arg) * rs;
  }
}

// ---------------- bf16 MFMA GEMM: C[M,N] = A[M,K] @ Bt[N,K]^T ----------------
// Dual-LDS-staged, BK=64, XOR-octet swizzle (linear global_load_lds dest,
// pre-swizzled global source, same XOR on ds_read).
template<int EPI, int BN>
__device__ __forceinline__ void gemm_body(
    const u16* __restrict__ A, const u16* __restrict__ Bt,
    const float* __restrict__ bias, const float* __restrict__ R,
    float* __restrict__ Cf, u16* __restrict__ Cbf,
    int N, int K, int bx, int by) {
  constexpr int NI = BN / 32;          // B fragments per wave
  constexpr int BK = 64;               // K-chunk
  __shared__ u16 Al[128 * BK];
  __shared__ u16 Bl[BN * BK];
  int tid = threadIdx.x;
  int wv = tid >> 6, ln = tid & 63;
  int wr = wv >> 1, wc = wv & 1;
  int lhi = ln >> 4, llo = ln & 15;
  int bm = bx * 128, bn = by * BN;

  f32x4 zero = {0.f, 0.f, 0.f, 0.f};
  f32x4 acc[4][NI];
  #pragma unroll
  for (int mi = 0; mi < 4; ++mi)
    #pragma unroll
    for (int ni = 0; ni < NI; ++ni) acc[mi][ni] = zero;

  for (int k0 = 0; k0 < K; k0 += BK) {
    if (k0) __syncthreads();
    #pragma unroll
    for (int i = 0; i < 128 * BK / (8 * 256); ++i) {   // 4
      int f = i * 256 + tid;
      int r = f >> 3, o = f & 7;
      load_lds16(A + (size_t)(bm + r) * K + k0 + ((o ^ (r & 7)) << 3),
                 &Al[(i * 256 + wv * 64) * 8]);
    }
    #pragma unroll
    for (int i = 0; i < BN * BK / (8 * 256); ++i) {    // 4 or 2
      int f = i * 256 + tid;
      int r = f >> 3, o = f & 7;
      load_lds16(Bt + (size_t)(bn + r) * K + k0 + ((o ^ (r & 7)) << 3),
                 &Bl[(i * 256 + wv * 64) * 8]);
    }
    __syncthreads();
    #pragma unroll
    for (int ks = 0; ks < BK; ks += 32) {
      short8 af[4], bf[NI];
      #pragma unroll
      for (int mi = 0; mi < 4; ++mi) {
        int row = wr * 64 + mi * 16 + llo;
        int oct = ((ks >> 3) + lhi) ^ (llo & 7);
        af[mi] = *(const short8*)&Al[row * BK + oct * 8];
      }
      #pragma unroll
      for (int ni = 0; ni < NI; ++ni) {
        int row = wc * (BN / 2) + ni * 16 + llo;
        int oct = ((ks >> 3) + lhi) ^ (llo & 7);
        bf[ni] = *(const short8*)&Bl[row * BK + oct * 8];
      }
      #pragma unroll
      for (int mi = 0; mi < 4; ++mi)
        #pragma unroll
        for (int ni = 0; ni < NI; ++ni)
          acc[mi][ni] = __builtin_amdgcn_mfma_f32_16x16x32_bf16(
              af[mi], bf[ni], acc[mi][ni], 0, 0, 0);
    }
  }

  // Epilogue. C/D layout: col = lane&15, row = (lane>>4)*4 + reg.
  #pragma unroll
  for (int mi = 0; mi < 4; ++mi) {
    #pragma unroll
    for (int r = 0; r < 4; ++r) {
      int row = bm + wr * 64 + mi * 16 + lhi * 4 + r;
      #pragma unroll
      for (int ni = 0; ni < NI; ++ni) {
        int col = bn + wc * (BN / 2) + ni * 16 + llo;
        float val = acc[mi][ni][r] + bias[col];
        if (EPI == 1) {
          val += R[(size_t)row * N + col];
          Cf[(size_t)row * N + col] = val;
        } else {
          if (EPI == 2) val = gelu_exact(val);
          Cbf[(size_t)row * N + col] = f2b(val);
        }
      }
    }
  }
}

// 1-D grid + XCD-chunk swizzle (by fast -> A re-reads hit local L2)
template<int EPI, int BN, int NY>
__global__ __launch_bounds__(256) void gemm_swz_kernel(
    const u16* __restrict__ A, const u16* __restrict__ Bt,
    const float* __restrict__ bias, const float* __restrict__ R,
    float* __restrict__ Cf, u16* __restrict__ Cbf, int N, int K) {
  int cpx = gridDim.x >> 3;            // grid multiple of 8
  int orig = blockIdx.x;
  int swz = (orig & 7) * cpx + (orig >> 3);
  int bx = swz / NY, by = swz % NY;
  gemm_body<EPI, BN>(A, Bt, bias, R, Cf, Cbf, N, K, bx, by);
}

__global__ __launch_bounds__(256) void qkv_kernel(
    const u16* __restrict__ A,
    const u16* __restrict__ Bq, const u16* __restrict__ Bk, const u16* __restrict__ Bv,
    const float* __restrict__ bq, const float* __restrict__ bk, const float* __restrict__ bv,
    u16* __restrict__ q, u16* __restrict__ k, u16* __restrict__ v) {
  int cpx = gridDim.x >> 3;            // 768 -> 96
  int orig = blockIdx.x;
  int swz = (orig & 7) * cpx + (orig >> 3);
  int bx = swz / 6, y = swz % 6;       // y fast: all 6 N/sel-blocks share A-panel
  int sel = y >> 1;
  const u16* Bt = sel == 0 ? Bq : sel == 1 ? Bk : Bv;
  const float* bias = sel == 0 ? bq : sel == 1 ? bk : bv;
  u16* C = sel == 0 ? q : sel == 1 ? k : v;
  gemm_body<0, 128>(A, Bt, bias, nullptr, nullptr, C, 256, 256, bx, y & 1);
}

// ---------------- fused attn + Wo GEMM + residual + LN2 ----------------
__global__ __launch_bounds__(512) void awo_ln_kernel(
    const u16* __restrict__ q, const u16* __restrict__ k,
    const u16* __restrict__ v, const int* __restrict__ nidx,
    const float* __restrict__ ndist, const float* __restrict__ log_tau,
    const u16* __restrict__ Bt, const float* __restrict__ bo,
    const float* __restrict__ xres,
    const float* __restrict__ ln2w, const float* __restrict__ ln2b,
    float* __restrict__ x2, u16* __restrict__ tln) {
  __shared__ u16 Al[64 * 256];     // 32 KB, octet-swizzled, full K
  __shared__ u16 Bl[256 * 64];     // 32 KB
  __shared__ float red[4][64][2];  // 2 KB
  int tid = threadIdx.x;
  int bm = blockIdx.x * 64;

  // ---- phase 1: gathered attention ----
  {
    int rl = tid >> 3, h = tid & 7;
    int row = bm + rl;
    int b = row >> 12;
    float rtau = 1.0f / (expf(log_tau[0]) + kEps);
    const u16x8* qr = (const u16x8*)(q + (size_t)row * kDim + h * 32);
    float qf[32];
    #pragma unroll
    for (int cch = 0; cch < 4; ++cch) {
      u16x8 u = qr[cch];
      #pragma unroll
      for (int e = 0; e < 8; ++e) qf[cch * 8 + e] = b2f(u[e]);
    }
    int njs[kK];
    float sc[kK];
    const int* ir = nidx + (size_t)row * kK;
    const float* dr = ndist + (size_t)row * kK;
    float smax = -1e30f;
    #pragma unroll
    for (int j = 0; j < kK; ++j) {
      int nj = ir[j];
      njs[j] = nj;
      const u16x8* kr = (const u16x8*)(k + ((size_t)b * kN + nj) * kDim + h * 32);
      float dot = 0.0f;
      #pragma unroll
      for (int cch = 0; cch < 4; ++cch) {
        u16x8 u = kr[cch];
        #pragma unroll
        for (int e = 0; e < 8; ++e) dot = fmaf(qf[cch * 8 + e], b2f(u[e]), dot);
      }
      float s = dot * 0.17677669529663687f - dr[j] * rtau;  // 1/sqrt(32)
      sc[j] = s;
      smax = fmaxf(smax, s);
    }
    float sum = 0.0f;
    #pragma unroll
    for (int j = 0; j < kK; ++j) { sc[j] = expf(sc[j] - smax); sum += sc[j]; }
    float rsum = 1.0f / sum;
    float o[32];
    #pragma unroll
    for (int d = 0; d < 32; ++d) o[d] = 0.0f;
    #pragma unroll
    for (int j = 0; j < kK; ++j) {
      float p = sc[j] * rsum;
      const u16x8* vr = (const u16x8*)(v + ((size_t)b * kN + njs[j]) * kDim + h * 32);
      #pragma unroll
      for (int cch = 0; cch < 4; ++cch) {
        u16x8 u = vr[cch];
        #pragma unroll
        for (int e = 0; e < 8; ++e) o[cch * 8 + e] = fmaf(p, b2f(u[e]), o[cch * 8 + e]);
      }
    }
    #pragma unroll
    for (int cch = 0; cch < 4; ++cch) {
      u16x8 po;
      #pragma unroll
      for (int e = 0; e < 8; ++e) po[e] = f2b(o[cch * 8 + e]);
      int oct = h * 4 + cch;
      *(u16x8*)&Al[rl * 256 + ((oct ^ (rl & 7)) << 3)] = po;
    }
  }
  __syncthreads();

  // ---- phase 2: GEMM (A resident in LDS) ----
  int wv = tid >> 6, ln = tid & 63;
  int wr = wv >> 2, wc = wv & 3;
  int lhi = ln >> 4, llo = ln & 15;

  f32x4 zero = {0.f, 0.f, 0.f, 0.f};
  f32x4 acc[2][4];
  #pragma unroll
  for (int mi = 0; mi < 2; ++mi)
    #pragma unroll
    for (int ni = 0; ni < 4; ++ni) acc[mi][ni] = zero;

  for (int k0 = 0; k0 < 256; k0 += 64) {
    if (k0) __syncthreads();
    #pragma unroll
    for (int i = 0; i < 4; ++i) {  // B: 256x64
      int f = i * 512 + tid, r = f >> 3, o = f & 7;
      load_lds16(Bt + (size_t)r * 256 + k0 + ((o ^ (r & 7)) << 3),
                 &Bl[((i * 8 + wv) * 64) * 8]);
    }
    __syncthreads();
    #pragma unroll
    for (int ks = 0; ks < 64; ks += 32) {
      short8 af[2], bf[4];
      #pragma unroll
      for (int mi = 0; mi < 2; ++mi) {
        int row = wr * 32 + mi * 16 + llo;
        int octg = ((k0 + ks) >> 3) + lhi;
        af[mi] = *(const short8*)&Al[row * 256 + ((octg ^ (llo & 7)) << 3)];
      }
      #pragma unroll
      for (int ni = 0; ni < 4; ++ni) {
        int brow = wc * 64 + ni * 16 + llo;
        int oct = ((ks >> 3) + lhi) ^ (llo & 7);
        bf[ni] = *(const short8*)&Bl[brow * 64 + oct * 8];
      }
      #pragma unroll
      for (int mi = 0; mi < 2; ++mi)
        #pragma unroll
        for (int ni = 0; ni < 4; ++ni)
          acc[mi][ni] = __builtin_amdgcn_mfma_f32_16x16x32_bf16(
              af[mi], bf[ni], acc[mi][ni], 0, 0, 0);
    }
  }

  float psum[2][4], psq[2][4];
  #pragma unroll
  for (int mi = 0; mi < 2; ++mi) {
    #pragma unroll
    for (int r = 0; r < 4; ++r) {
      int row = bm + wr * 32 + mi * 16 + lhi * 4 + r;
      float s = 0.0f, qv = 0.0f;
      #pragma unroll
      for (int ni = 0; ni < 4; ++ni) {
        int col = wc * 64 + ni * 16 + llo;
        float vv = acc[mi][ni][r] + bo[col] + xres[(size_t)row * 256 + col];
        acc[mi][ni][r] = vv;
        s += vv;
        qv = fmaf(vv, vv, qv);
      }
      #pragma unroll
      for (int off = 1; off < 16; off <<= 1) {
        s += __shfl_xor(s, off);
        qv += __shfl_xor(qv, off);
      }
      psum[mi][r] = s; psq[mi][r] = qv;
    }
  }
  if (llo == 0) {
    #pragma unroll
    for (int mi = 0; mi < 2; ++mi)
      #pragma unroll
      for (int r = 0; r < 4; ++r) {
        int rl = wr * 32 + mi * 16 + lhi * 4 + r;
        red[wc][rl][0] = psum[mi][r];
        red[wc][rl][1] = psq[mi][r];
      }
  }
  __syncthreads();
  constexpr float rn = 1.0f / 256.0f;
  #pragma unroll
  for (int mi = 0; mi < 2; ++mi) {
    #pragma unroll
    for (int r = 0; r < 4; ++r) {
      int rl = wr * 32 + mi * 16 + lhi * 4 + r;
      int row = bm + rl;
      float S = red[0][rl][0] + red[1][rl][0] + red[2][rl][0] + red[3][rl][0];
      float Q = red[0][rl][1] + red[1][rl][1] + red[2][rl][1] + red[3][rl][1];
      float mean = S * rn;
      float var = Q * rn - mean * mean;
      float rstd = rsqrtf(var + 1e-5f);
      #pragma unroll
      for (int ni = 0; ni < 4; ++ni) {
        int col = wc * 64 + ni * 16 + llo;
        float vv = acc[mi][ni][r];
        x2[(size_t)row * 256 + col] = vv;
        tln[(size_t)row * 256 + col] =
            f2b((vv - mean) * rstd * ln2w[col] + ln2b[col]);
      }
    }
  }
}

}  // namespace

extern "C" void kernel_launch(void* const* d_in, const int* in_sizes, int n_in,
                              void* d_out, int out_size, void* d_ws, size_t ws_size,
                              hipStream_t stream) {
  const float* x    = (const float*)d_in[0];
  const float* pos  = (const float*)d_in[1];
  const float* c    = (const float*)d_in[2];
  const float* temb = (const float*)d_in[3];
  const float* Wq   = (const float*)d_in[4];
  const float* bq   = (const float*)d_in[5];
  const float* Wk   = (const float*)d_in[6];
  const float* bk   = (const float*)d_in[7];
  const float* Wv   = (const float*)d_in[8];
  const float* bv   = (const float*)d_in[9];
  const float* Wo   = (const float*)d_in[10];
  const float* bo   = (const float*)d_in[11];
  const float* W1   = (const float*)d_in[12];
  const float* b1   = (const float*)d_in[13];
  const float* W2   = (const float*)d_in[14];
  const float* b2   = (const float*)d_in[15];
  const float* ln1w = (const float*)d_in[16];
  const float* ln1b = (const float*)d_in[17];
  const float* ln2w = (const float*)d_in[18];
  const float* ln2b = (const float*)d_in[19];
  const float* ltau = (const float*)d_in[20];

  const size_t MB = 1ull << 20;
  char* w = (char*)d_ws;
  u16*   h_bf  = (u16*)(w + 0 * MB);               // [M,256] bf16 (8 MB); reused as tln
  u16*   qb    = (u16*)(w + 8 * MB);
  u16*   kb    = (u16*)(w + 16 * MB);
  u16*   vb    = (u16*)(w + 24 * MB);
  float* x2    = (float*)(w + 40 * MB);            // [M,256] f32 (16 MB)
  u16*   g_bf  = (u16*)(w + 56 * MB);              // [M,1024] bf16 (32 MB)
  u16*   wq_t  = (u16*)(w + 88 * MB);              // 128 KB each
  u16*   wk_t  = wq_t + 65536;
  u16*   wv_t  = wq_t + 2 * 65536;
  u16*   wo_t  = wq_t + 3 * 65536;
  u16*   w1_t  = (u16*)(w + 89 * MB);              // [1024][256] (512 KB)
  u16*   w2_t  = (u16*)(w + 89 * MB + 512 * 1024); // [256][1024] (512 KB)
  int*   kidx  = (int*)(w + 90 * MB);              // [M,16]
  float* kdst  = (float*)(w + 91 * MB);            // [M,16]
  u16*   tln   = h_bf;

  // 1. fused front: topk (1024 blk) + wtrans (192 blk) + LN1 (1024 blk)
  hipLaunchKernelGGL(front_kernel, dim3(2240), dim3(1024), 0, stream,
                     pos, c, kidx, kdst,
                     x, ln1w, ln1b, temb, h_bf,
                     Wq, Wk, Wv, Wo, W1, W2, wq_t, wk_t, wv_t, wo_t, w1_t, w2_t);
  // 2. fused Q,K,V MFMA GEMM (XCD-chunk swizzled 1-D grid)
  hipLaunchKernelGGL(qkv_kernel, dim3(768), dim3(256), 0, stream,
                     h_bf, wq_t, wk_t, wv_t, bq, bk, bv, qb, kb, vb);
  // 3. gathered attention + Wo + residual + LN2 (fused)
  hipLaunchKernelGGL(awo_ln_kernel, dim3(256), dim3(512), 0, stream,
                     qb, kb, vb, kidx, kdst, ltau,
                     wo_t, bo, x, ln2w, ln2b, x2, tln);
  // 4. g = gelu(tln @ W1 + b1)  (bf16), swizzled
  hipLaunchKernelGGL((gemm_swz_kernel<2, 128, 8>), dim3(1024), dim3(256), 0, stream,
                     tln, w1_t, b1, nullptr, (float*)nullptr, g_bf, 1024, 256);
  // 5. out = x2 + g @ W2 + b2  (f32), swizzled
  hipLaunchKernelGGL((gemm_swz_kernel<1, 64, 4>), dim3(512), dim3(256), 0, stream,
                     g_bf, w2_t, b2, x2, (float*)d_out, (u16*)nullptr, 256, 1024);
}